// Round 15
// baseline (192.802 us; speedup 1.0000x reference)
//
#include <hip/hip_runtime.h>
#include <type_traits>

#define S_LEN 2048
#define HID   768
#define NHEAD 12
#define HDIM  64
#define BATCH 4

typedef __attribute__((ext_vector_type(4))) float float4v;
typedef __attribute__((ext_vector_type(8))) short short8;
typedef __attribute__((ext_vector_type(4))) short short4v;
typedef __attribute__((ext_vector_type(2))) int int2v;
typedef __attribute__((ext_vector_type(4))) int int4v;

__device__ __forceinline__ short f2b(float f) {
  unsigned u = __float_as_uint(f);
  u += 0x7fff + ((u >> 16) & 1);   // RNE
  return (short)(u >> 16);
}

__device__ __forceinline__ unsigned pkbf(float a, float b) {
#if __has_builtin(__builtin_amdgcn_cvt_pk_bf16_f32)
  typedef __attribute__((ext_vector_type(2))) __bf16 bf2;
  bf2 r = __builtin_amdgcn_cvt_pk_bf16_f32(a, b);
  return *(unsigned*)&r;
#else
  return ((unsigned)(unsigned short)f2b(a)) |
         (((unsigned)(unsigned short)f2b(b)) << 16);
#endif
}

__device__ __forceinline__ float fexp2(float x) {
#if __has_builtin(__builtin_amdgcn_exp2f)
  return __builtin_amdgcn_exp2f(x);
#else
  return __expf(x * 0.69314718056f);
#endif
}

// async global->LDS, 16 B per lane; lds base must be wave-uniform
__device__ __forceinline__ void g2l16(const short* g, short* l) {
  __builtin_amdgcn_global_load_lds(
      (const __attribute__((address_space(1))) void*)g,
      (__attribute__((address_space(3))) void*)l, 16, 0, 0);
}

// ---------------- fused pre-pass: cvt x + transpose both weights ----------------
__global__ __launch_bounds__(256) void prepass(const float* __restrict__ x,
                                               const float* __restrict__ w_qkv,
                                               const float* __restrict__ w_out,
                                               short* __restrict__ xb,
                                               short* __restrict__ wqkvT,
                                               short* __restrict__ woutT) {
  __shared__ float tile[64][65];
  const int blk = blockIdx.x;
  if (blk < 3072) {  // cvt: 2048 elems per block
    int i = blk * 2048 + threadIdx.x * 8;
    float4v a = *(const float4v*)&x[i];
    float4v b = *(const float4v*)&x[i + 4];
    short8 o;
#pragma unroll
    for (int j = 0; j < 4; j++) { o[j] = f2b(a[j]); o[j + 4] = f2b(b[j]); }
    *(short8*)&xb[i] = o;
    return;
  }
  const float* W; short* WT; int N_, scaleN, idx;
  if (blk < 3504) { idx = blk - 3072; W = w_qkv; WT = wqkvT; N_ = 3 * HID; scaleN = HID; }
  else            { idx = blk - 3504; W = w_out; WT = woutT; N_ = HID;     scaleN = 0;  }
  const int nblk = N_ / 64;
  const int n0 = (idx % nblk) * 64, k0 = (idx / nblk) * 64;
  const int tx = threadIdx.x & 63, ty = threadIdx.x >> 6;
#pragma unroll
  for (int r = 0; r < 16; r++) {
    int row = r * 4 + ty;
    tile[row][tx] = W[(size_t)(k0 + row) * N_ + n0 + tx];
  }
  __syncthreads();
#pragma unroll
  for (int r = 0; r < 16; r++) {
    int row = r * 4 + ty;
    float sc = (n0 + row < scaleN) ? 0.18033688011f : 1.0f;  // 0.125*log2e
    WT[(size_t)(n0 + row) * HID + k0 + tx] = f2b(tile[tx][row] * sc);
  }
}

// ---------------- bf16 GEMM: C[MxN] = A[MxK] * Bt[NxK]^T ----------
// round-23: 128(M) x 64(N) tile — fixes grid-bound occupancy.
// Diagnosis r14: V/out gemms had only 384 blocks = 1.5 blocks/CU (QK 3.0);
// at 1-2 blocks/CU the per-k-step vmcnt(0) drain has no other-block waves
// to hide behind (this is also why r4/r10's intra-block pipelines failed —
// they attacked the wrong axis and paid LDS for it).  N-tile 64 doubles
// every grid: QK 1536 (6/CU), V/out 768 (3/CU).  LDS 32->24 KB.
// Inner loop, XOR swizzle, epilogue layouts identical to the r6-proven
// structure; waves now 2M x 2N owning 64x32 (acc[4][2]); B staged with one
// g2l16 per wave per sub-buffer (64 rows).
//   * OUT: 0 = float C, 1 = Q/K bf16, 2 = V with swapped MFMA operands
//     (transposed acc -> vT[d][s] stores land along s; traffic-verified r4).
//   * XCD-chunked block swizzle (nwg%8==0 all launches); m-major flat =>
//     consecutive blocks on an XCD share the A panel (L2 reuse).
template <int OUT>
__global__ __launch_bounds__(256) void gemm_bt(const short* __restrict__ A,
                                               const short* __restrict__ Bt,
                                               float* __restrict__ Cf,
                                               short* __restrict__ Cq,
                                               short* __restrict__ vT,
                                               int M, int N, int K) {
  __shared__ __align__(16) short As[2][128 * 32];
  __shared__ __align__(16) short Bs[2][64 * 32];
  const int tid = threadIdx.x;
  const int w = tid >> 6, lane = tid & 63;
  const int quad = lane >> 4, lm = lane & 15;

  const int gx = gridDim.x;
  const int nwg = gx * gridDim.y;
  int flat = blockIdx.y * gx + blockIdx.x;
  if ((nwg & 7) == 0) flat = (flat & 7) * (nwg >> 3) + (flat >> 3);
  const int m0 = (flat / gx) * 128, n0 = (flat % gx) * 64;
  const int mo = (w & 1) * 64, no = (w >> 1) * 32;

  float4v acc[4][2];
#pragma unroll
  for (int i = 0; i < 4; i++)
#pragma unroll
    for (int j = 0; j < 2; j++) acc[i][j] = (float4v)0.0f;

  // staging: linear LDS dest; source column chunk pre-swizzled so that
  // LDS[row][slot] holds global chunk slot^((row>>1)&3)
  const int srow = w * 32 + (lane >> 2);       // A rows: 4 waves x 32 = 128
  const int srowB = w * 16 + (lane >> 2);      // B rows: 4 waves x 16 = 64
  const int scol = ((lane & 3) ^ ((lane >> 3) & 3)) * 8;
  const short* Ag = A + (size_t)(m0 + srow) * K + scol;
  const short* Bg = Bt + (size_t)(n0 + srowB) * K + scol;

  // read-side: lane-constant swizzled slot
  const int qsw8 = (quad ^ ((lm >> 1) & 3)) * 8;

  for (int kb = 0; kb < K; kb += 64) {
#pragma unroll
    for (int s = 0; s < 2; s++) {
      short* Al = &As[s][(w * 32) * 32];
      short* Bl = &Bs[s][(w * 16) * 32];
      g2l16(Ag + kb + s * 32, Al);
      g2l16(Ag + kb + s * 32 + (size_t)16 * K, Al + 16 * 32);
      g2l16(Bg + kb + s * 32, Bl);
    }
    __syncthreads();

#pragma unroll
    for (int s = 0; s < 2; s++) {
      short8 af[4], bf[2];
#pragma unroll
      for (int i = 0; i < 4; i++)
        af[i] = *(const short8*)&As[s][(mo + i * 16 + lm) * 32 + qsw8];
#pragma unroll
      for (int j = 0; j < 2; j++)
        bf[j] = *(const short8*)&Bs[s][(no + j * 16 + lm) * 32 + qsw8];
#pragma unroll
      for (int i = 0; i < 4; i++)
#pragma unroll
        for (int j = 0; j < 2; j++) {
          if constexpr (OUT == 2)
            acc[i][j] = __builtin_amdgcn_mfma_f32_16x16x32_bf16(bf[j], af[i], acc[i][j], 0, 0, 0);
          else
            acc[i][j] = __builtin_amdgcn_mfma_f32_16x16x32_bf16(af[i], bf[j], acc[i][j], 0, 0, 0);
        }
    }
    __syncthreads();
  }

  if constexpr (OUT == 0) {
#pragma unroll
    for (int i = 0; i < 4; i++)
#pragma unroll
      for (int j = 0; j < 2; j++)
#pragma unroll
        for (int r = 0; r < 4; r++)
          Cf[(size_t)(m0 + mo + i * 16 + quad * 4 + r) * N + n0 + no + j * 16 + lm] =
              acc[i][j][r];
  } else if constexpr (OUT == 1) {  // Q/K tile -> qk[m][1536]
#pragma unroll
    for (int i = 0; i < 4; i++)
#pragma unroll
      for (int j = 0; j < 2; j++)
#pragma unroll
        for (int r = 0; r < 4; r++)
          Cq[(size_t)(m0 + mo + i * 16 + quad * 4 + r) * (2 * HID) + n0 + no + j * 16 + lm] =
              f2b(acc[i][j][r]);
  } else {  // V tile (swapped acc: rows=n/d, cols=m/s) -> vT[b][h][d][s]
    const int b = m0 >> 11;
#pragma unroll
    for (int i = 0; i < 4; i++) {
      const int sG = (m0 & 2047) + mo + i * 16 + lm;
#pragma unroll
      for (int j = 0; j < 2; j++) {
#pragma unroll
        for (int r = 0; r < 4; r++) {
          int col = n0 + no + j * 16 + quad * 4 + r;   // 0..767 (V block local)
          int h = col >> 6, d = col & 63;
          vT[((size_t)(b * NHEAD + h) * HDIM + d) * S_LEN + sG] = f2b(acc[i][j][r]);
        }
      }
    }
  }
}

// ---------------- MFMA flash attention (round-14 version, unchanged) ----
// in-register P via swapped QK^T + chosen K staging permutation; no Ps LDS.
// 48.2us, occ 31%, VGPR 44, LDS 32KB, conflicts 0.
__global__ __launch_bounds__(256) void attn_mfma(const short* __restrict__ qk,
                                                 const short* __restrict__ vT,
                                                 short* __restrict__ attnout) {
  __shared__ __align__(16) short Ks[2][64 * 64];   // [p][d], p key-permuted, swizzled
  __shared__ __align__(16) short Vt[2][64 * 64];   // [d][key], swizzled

  const int tid = threadIdx.x;
  const int w = tid >> 6, lane = tid & 63;
  const int quad = lane >> 4, lm = lane & 15;
  const int bh = blockIdx.x;
  const int qt = 31 - blockIdx.y;        // longest-first dispatch order
  const int b = bh / NHEAD, h = bh % NHEAD;

  // ---- Q fragments in registers ----
  short8 aq[2];
#pragma unroll
  for (int kb = 0; kb < 2; kb++)
    aq[kb] = *(const short8*)&qk[(size_t)(b * S_LEN + qt * 64 + w * 16 + lm) * (2 * HID) +
                                 h * HDIM + kb * 32 + quad * 8];

  // ---- register constants ----
  const float4v z4 = (float4v)0.0f;       // C operand for first-kb MFMA
  short8 one8;                            // bf16 1.0 broadcast (B-frag of ones)
#pragma unroll
  for (int j = 0; j < 8; j++) one8[j] = (short)0x3F80;

  // ---- per-lane DMA source pointers (inverse swizzle + key permutation
  //      pre-applied; LDS dest linear; bump-by-constant each issue) ----
  const size_t kbase = (size_t)(b * S_LEN) * (2 * HID) + HID + h * HDIM;
  const size_t vbase = (size_t)(b * NHEAD + h) * HDIM * S_LEN;
  const short* kptr[2];
  const short* vptr[2];
#pragma unroll
  for (int i = 0; i < 2; i++) {
    int c = (w * 2 + i) * 64 + lane;       // LDS 16B-chunk index this lane writes
    int row = c >> 3, slot = c & 7;
    int q8 = slot ^ (row & 7);             // inverse-swizzled source chunk
    int ra = row & 15, nt = row >> 4;
    // key permutation making PV A-frag keys lane-local after swapped QK^T:
    int key = 8 * (ra >> 2) + 2 * (ra & 3) + (nt & 1) + 32 * (nt >> 1);
    kptr[i] = qk + kbase + (size_t)key * (2 * HID) + q8 * 8;
    vptr[i] = vT + vbase + (size_t)row * S_LEN + q8 * 8;
  }

#define ISSUE(BUF)                                                    \
  {                                                                   \
    _Pragma("unroll") for (int i = 0; i < 2; i++) {                   \
      g2l16(kptr[i], &Ks[BUF][(w * 2 + i) * 512]);                    \
      g2l16(vptr[i], &Vt[BUF][(w * 2 + i) * 512]);                    \
      kptr[i] += 64 * 2 * HID;                                        \
      vptr[i] += 64;                                                  \
    }                                                                 \
  }

  // ---- hoisted LDS read addressing ----
  const int swx = (lm & 7) << 4;
  const int loff0 = (quad * 16) ^ swx;          // kb=0 lane part
  const int loff1 = (64 + quad * 16) ^ swx;     // kb=1 lane part
  const int rowK = lm << 7;
  const char* KsB = (const char*)&Ks[0][0];
  const char* VtB = (const char*)&Vt[0][0];

  float4v o_acc[4];
#pragma unroll
  for (int nt = 0; nt < 4; nt++) o_acc[nt] = (float4v)0.0f;
  float4v o1 = (float4v)0.0f;                   // P row-sum accumulator

  const int ktmax = qt + 1;
  int cur = 0;

  ISSUE(0);

  for (int kt = 0; kt < ktmax; kt++) {
    // drain our in-flight DMA for buf[cur], and fence buf[cur^1] readers
    asm volatile("s_waitcnt vmcnt(0)" ::: "memory");
    __syncthreads();
    if (kt + 1 < ktmax) ISSUE(cur ^ 1);

    const int coff = cur << 13;
    const char* kB0 = KsB + coff + rowK + loff0;
    const char* kB1 = KsB + coff + rowK + loff1;
    const char* vB0 = VtB + coff + rowK + loff0;
    const char* vB1 = VtB + coff + rowK + loff1;

    // QK^T with SWAPPED operands: P[key][qrow], qrow = col = lane's lm.
    float4v s_acc[4];
    __builtin_amdgcn_s_setprio(1);
#pragma unroll
    for (int nt = 0; nt < 4; nt++) {
      short8 bk = *(const short8*)(kB0 + nt * 2048);
      s_acc[nt] = __builtin_amdgcn_mfma_f32_16x16x32_bf16(bk, aq[0], z4, 0, 0, 0);
    }
#pragma unroll
    for (int nt = 0; nt < 4; nt++) {
      short8 bk = *(const short8*)(kB1 + nt * 2048);
      s_acc[nt] = __builtin_amdgcn_mfma_f32_16x16x32_bf16(bk, aq[1], s_acc[nt], 0, 0, 0);
    }
    __builtin_amdgcn_s_setprio(0);

    // lane(quad,lm) holds P[qrow=w*16+lm][key = 8*quad+2*r+(nt&1)+32*(nt>>1)]
    const bool diag = (kt == qt);
    float e[4][4];
#pragma unroll
    for (int nt = 0; nt < 4; nt++)
#pragma unroll
      for (int r = 0; r < 4; r++) {
        float v = fexp2(s_acc[nt][r]);  // Q pre-scaled by 0.125*log2e
        if (diag && (8 * quad + 2 * r + (nt & 1) + 32 * (nt >> 1) > w * 16 + lm)) v = 0.0f;
        e[nt][r] = v;
      }

    // pack in-register into PV A-fragments (keys 32*kb+quad*8+0..7)
    int4v p0i = {(int)pkbf(e[0][0], e[1][0]), (int)pkbf(e[0][1], e[1][1]),
                 (int)pkbf(e[0][2], e[1][2]), (int)pkbf(e[0][3], e[1][3])};
    int4v p1i = {(int)pkbf(e[2][0], e[3][0]), (int)pkbf(e[2][1], e[3][1]),
                 (int)pkbf(e[2][2], e[3][2]), (int)pkbf(e[2][3], e[3][3])};
    union UU { int4v i; short8 s; };
    UU u0, u1;
    u0.i = p0i;
    u1.i = p1i;
    short8 ap0 = u0.s, ap1 = u1.s;

    __builtin_amdgcn_s_setprio(1);
    o1 = __builtin_amdgcn_mfma_f32_16x16x32_bf16(ap0, one8, o1, 0, 0, 0);
#pragma unroll
    for (int nt = 0; nt < 4; nt++) {
      short8 bv = *(const short8*)(vB0 + nt * 2048);
      o_acc[nt] = __builtin_amdgcn_mfma_f32_16x16x32_bf16(ap0, bv, o_acc[nt], 0, 0, 0);
    }
    o1 = __builtin_amdgcn_mfma_f32_16x16x32_bf16(ap1, one8, o1, 0, 0, 0);
#pragma unroll
    for (int nt = 0; nt < 4; nt++) {
      short8 bv = *(const short8*)(vB1 + nt * 2048);
      o_acc[nt] = __builtin_amdgcn_mfma_f32_16x16x32_bf16(ap1, bv, o_acc[nt], 0, 0, 0);
    }
    __builtin_amdgcn_s_setprio(0);

    cur ^= 1;
  }

#pragma unroll
  for (int r = 0; r < 4; r++) {
    float inv = 1.0f / o1[r];             // row-sum from ones-MFMA (col-uniform)
    int rowg = b * S_LEN + qt * 64 + w * 16 + quad * 4 + r;
#pragma unroll
    for (int nt = 0; nt < 4; nt++)
      attnout[(size_t)rowg * HID + h * HDIM + nt * 16 + lm] =
          f2b(o_acc[nt][r] * inv);
  }
#undef ISSUE
}

extern "C" void kernel_launch(void* const* d_in, const int* in_sizes, int n_in,
                              void* d_out, int out_size, void* d_ws, size_t ws_size,
                              hipStream_t stream) {
  const float* x     = (const float*)d_in[0];
  const float* w_qkv = (const float*)d_in[1];
  const float* w_out = (const float*)d_in[2];
  float* out = (float*)d_out;

  const int M = BATCH * S_LEN;  // 8192
  short* qk     = (short*)d_ws;                       // [8192][1536] bf16
  short* attn   = qk + (size_t)M * 2 * HID;           // [8192][768]  bf16
  short* vT     = attn + (size_t)M * HID;             // [B][NH][64][2048] bf16
  short* xb     = vT + (size_t)M * HID;               // [8192][768]  bf16
  short* wqkvT  = xb + (size_t)M * HID;               // [2304][768]  bf16 (Q rows pre-scaled)
  short* woutT  = wqkvT + (size_t)(3 * HID) * HID;    // [768][768]   bf16

  prepass<<<3648, 256, 0, stream>>>(x, w_qkv, w_out, xb, wqkvT, woutT);

  // Q/K columns (N=1536), N-tile=64: nwg = 24*64 = 1536 (%8==0, 6 blocks/CU)
  gemm_bt<1><<<dim3(2 * HID / 64, M / 128), 256, 0, stream>>>(
      xb, wqkvT, nullptr, qk, nullptr, M, 2 * HID, HID);
  // V columns (N=768), swapped-operand MFMA: nwg = 12*64 = 768 (%8==0, 3/CU)
  gemm_bt<2><<<dim3(HID / 64, M / 128), 256, 0, stream>>>(
      xb, wqkvT + (size_t)(2 * HID) * HID, nullptr, nullptr, vT, M, HID, HID);
  // one q-tile per block; qt = 31-blockIdx.y -> longest blocks first
  attn_mfma<<<dim3(BATCH * NHEAD, 32), 256, 0, stream>>>(qk, vT, attn);
  // out-proj (N=768): nwg = 12*64 = 768 (%8==0, 3/CU)
  gemm_bt<0><<<dim3(HID / 64, M / 128), 256, 0, stream>>>(
      attn, woutT, out, nullptr, nullptr, M, HID, HID);
}

// Round 16
// 190.095 us; speedup vs baseline: 1.0142x; 1.0142x over previous
//
#include <hip/hip_runtime.h>
#include <type_traits>

#define S_LEN 2048
#define HID   768
#define NHEAD 12
#define HDIM  64
#define BATCH 4

typedef __attribute__((ext_vector_type(4))) float float4v;
typedef __attribute__((ext_vector_type(8))) short short8;
typedef __attribute__((ext_vector_type(4))) short short4v;
typedef __attribute__((ext_vector_type(2))) int int2v;
typedef __attribute__((ext_vector_type(4))) int int4v;

union PU { int4v i; short8 s; };

__device__ __forceinline__ short f2b(float f) {
  unsigned u = __float_as_uint(f);
  u += 0x7fff + ((u >> 16) & 1);   // RNE
  return (short)(u >> 16);
}

__device__ __forceinline__ unsigned pkbf(float a, float b) {
#if __has_builtin(__builtin_amdgcn_cvt_pk_bf16_f32)
  typedef __attribute__((ext_vector_type(2))) __bf16 bf2;
  bf2 r = __builtin_amdgcn_cvt_pk_bf16_f32(a, b);
  return *(unsigned*)&r;
#else
  return ((unsigned)(unsigned short)f2b(a)) |
         (((unsigned)(unsigned short)f2b(b)) << 16);
#endif
}

__device__ __forceinline__ float fexp2(float x) {
#if __has_builtin(__builtin_amdgcn_exp2f)
  return __builtin_amdgcn_exp2f(x);
#else
  return __expf(x * 0.69314718056f);
#endif
}

// async global->LDS, 16 B per lane; lds base must be wave-uniform
__device__ __forceinline__ void g2l16(const short* g, short* l) {
  __builtin_amdgcn_global_load_lds(
      (const __attribute__((address_space(1))) void*)g,
      (__attribute__((address_space(3))) void*)l, 16, 0, 0);
}

// ---------------- fused pre-pass: cvt x + transpose both weights ----------------
__global__ __launch_bounds__(256) void prepass(const float* __restrict__ x,
                                               const float* __restrict__ w_qkv,
                                               const float* __restrict__ w_out,
                                               short* __restrict__ xb,
                                               short* __restrict__ wqkvT,
                                               short* __restrict__ woutT) {
  __shared__ float tile[64][65];
  const int blk = blockIdx.x;
  if (blk < 3072) {  // cvt: 2048 elems per block
    int i = blk * 2048 + threadIdx.x * 8;
    float4v a = *(const float4v*)&x[i];
    float4v b = *(const float4v*)&x[i + 4];
    short8 o;
#pragma unroll
    for (int j = 0; j < 4; j++) { o[j] = f2b(a[j]); o[j + 4] = f2b(b[j]); }
    *(short8*)&xb[i] = o;
    return;
  }
  const float* W; short* WT; int N_, scaleN, idx;
  if (blk < 3504) { idx = blk - 3072; W = w_qkv; WT = wqkvT; N_ = 3 * HID; scaleN = HID; }
  else            { idx = blk - 3504; W = w_out; WT = woutT; N_ = HID;     scaleN = 0;  }
  const int nblk = N_ / 64;
  const int n0 = (idx % nblk) * 64, k0 = (idx / nblk) * 64;
  const int tx = threadIdx.x & 63, ty = threadIdx.x >> 6;
#pragma unroll
  for (int r = 0; r < 16; r++) {
    int row = r * 4 + ty;
    tile[row][tx] = W[(size_t)(k0 + row) * N_ + n0 + tx];
  }
  __syncthreads();
#pragma unroll
  for (int r = 0; r < 16; r++) {
    int row = r * 4 + ty;
    float sc = (n0 + row < scaleN) ? 0.18033688011f : 1.0f;  // 0.125*log2e
    WT[(size_t)(n0 + row) * HID + k0 + tx] = f2b(tile[tx][row] * sc);
  }
}

// ---------------- bf16 GEMM: C[MxN] = A[MxK] * Bt[NxK]^T ----------
// r14-measured-best structure (128x128 tile; stage 8 loads, sync, compute
// BK=64, sync).  r4/r10 (pipelines) and r15 (N-tile 64) were all neutral or
// regressions — this is the proven local optimum.
//   * LDS slot XOR-swizzle -> 2 lanes/bank, conflicts ~0 (verified r6).
//   * OUT: 0 = float C, 1 = Q/K bf16, 2 = V with swapped MFMA operands
//     (transposed acc -> vT[d][s] stores land along s; traffic-verified r4).
//   * XCD-chunked block swizzle (nwg%8==0 all launches).
template <int OUT>
__global__ __launch_bounds__(256) void gemm_bt(const short* __restrict__ A,
                                               const short* __restrict__ Bt,
                                               float* __restrict__ Cf,
                                               short* __restrict__ Cq,
                                               short* __restrict__ vT,
                                               int M, int N, int K) {
  __shared__ __align__(16) short As[2][128 * 32];
  __shared__ __align__(16) short Bs[2][128 * 32];
  const int tid = threadIdx.x;
  const int w = tid >> 6, lane = tid & 63;
  const int quad = lane >> 4, lm = lane & 15;

  const int gx = gridDim.x;
  const int nwg = gx * gridDim.y;
  int flat = blockIdx.y * gx + blockIdx.x;
  if ((nwg & 7) == 0) flat = (flat & 7) * (nwg >> 3) + (flat >> 3);
  const int m0 = (flat / gx) * 128, n0 = (flat % gx) * 128;
  const int mo = (w & 1) * 64, no = (w >> 1) * 64;

  float4v acc[4][4];
#pragma unroll
  for (int i = 0; i < 4; i++)
#pragma unroll
    for (int j = 0; j < 4; j++) acc[i][j] = (float4v)0.0f;

  // staging: linear LDS dest; source column chunk pre-swizzled so that
  // LDS[row][slot] holds global chunk slot^((row>>1)&3)
  const int srow = w * 32 + (lane >> 2);
  const int scol = ((lane & 3) ^ ((lane >> 3) & 3)) * 8;
  const short* Ag = A + (size_t)(m0 + srow) * K + scol;
  const short* Bg = Bt + (size_t)(n0 + srow) * K + scol;

  // read-side: lane-constant swizzled slot
  const int qsw8 = (quad ^ ((lm >> 1) & 3)) * 8;

  for (int kb = 0; kb < K; kb += 64) {
#pragma unroll
    for (int s = 0; s < 2; s++) {
      short* Al = &As[s][(w * 32) * 32];
      short* Bl = &Bs[s][(w * 32) * 32];
      g2l16(Ag + kb + s * 32, Al);
      g2l16(Ag + kb + s * 32 + (size_t)16 * K, Al + 16 * 32);
      g2l16(Bg + kb + s * 32, Bl);
      g2l16(Bg + kb + s * 32 + (size_t)16 * K, Bl + 16 * 32);
    }
    __syncthreads();

#pragma unroll
    for (int s = 0; s < 2; s++) {
      short8 af[4], bf[4];
#pragma unroll
      for (int i = 0; i < 4; i++)
        af[i] = *(const short8*)&As[s][(mo + i * 16 + lm) * 32 + qsw8];
#pragma unroll
      for (int j = 0; j < 4; j++)
        bf[j] = *(const short8*)&Bs[s][(no + j * 16 + lm) * 32 + qsw8];
#pragma unroll
      for (int i = 0; i < 4; i++)
#pragma unroll
        for (int j = 0; j < 4; j++) {
          if constexpr (OUT == 2)
            acc[i][j] = __builtin_amdgcn_mfma_f32_16x16x32_bf16(bf[j], af[i], acc[i][j], 0, 0, 0);
          else
            acc[i][j] = __builtin_amdgcn_mfma_f32_16x16x32_bf16(af[i], bf[j], acc[i][j], 0, 0, 0);
        }
    }
    __syncthreads();
  }

  if constexpr (OUT == 0) {
#pragma unroll
    for (int i = 0; i < 4; i++)
#pragma unroll
      for (int j = 0; j < 4; j++)
#pragma unroll
        for (int r = 0; r < 4; r++)
          Cf[(size_t)(m0 + mo + i * 16 + quad * 4 + r) * N + n0 + no + j * 16 + lm] =
              acc[i][j][r];
  } else if constexpr (OUT == 1) {  // Q/K tile -> qk[m][1536]
#pragma unroll
    for (int i = 0; i < 4; i++)
#pragma unroll
      for (int j = 0; j < 4; j++)
#pragma unroll
        for (int r = 0; r < 4; r++)
          Cq[(size_t)(m0 + mo + i * 16 + quad * 4 + r) * (2 * HID) + n0 + no + j * 16 + lm] =
              f2b(acc[i][j][r]);
  } else {  // V tile (swapped acc: rows=n/d, cols=m/s) -> vT[b][h][d][s]
    const int b = m0 >> 11;
#pragma unroll
    for (int i = 0; i < 4; i++) {
      const int sG = (m0 & 2047) + mo + i * 16 + lm;
#pragma unroll
      for (int j = 0; j < 4; j++) {
#pragma unroll
        for (int r = 0; r < 4; r++) {
          int col = n0 + no + j * 16 + quad * 4 + r;   // 0..767 (V block local)
          int h = col >> 6, d = col & 63;
          vT[((size_t)(b * NHEAD + h) * HDIM + d) * S_LEN + sG] = f2b(acc[i][j][r]);
        }
      }
    }
  }
}

// ---------------- MFMA flash attention (round-25: cross-iteration pipeline) ----
// r14's in-register-P body is chain-serial per iteration: QK -> exp -> PV
// (VALU 50%, MFMA 24%, neither saturated -> latency-bound).  The compiler
// cannot rotate that loop.  This round lags PV by one iteration: at kt we
// issue QK(kt), then PV(kt-1) (independent of QK(kt)), then exp(kt).  PV's
// 10 MFMAs cover the QK->exp dependency; exp's VALU runs under PV's matrix
// time.  V gets 3 LDS slots (write kt+1 / hold kt / read kt-1, distinct
// mod 3) -> LDS 40 KB, 4 blocks/CU (proven sufficient at r8).  +16 VGPR
// for the carried P pair.
__global__ __launch_bounds__(256) void attn_mfma(const short* __restrict__ qk,
                                                 const short* __restrict__ vT,
                                                 short* __restrict__ attnout) {
  __shared__ __align__(16) short Ks[2][64 * 64];   // [p][d], p key-permuted, swizzled
  __shared__ __align__(16) short Vt[3][64 * 64];   // [d][key], swizzled, 3-slot

  const int tid = threadIdx.x;
  const int w = tid >> 6, lane = tid & 63;
  const int quad = lane >> 4, lm = lane & 15;
  const int bh = blockIdx.x;
  const int qt = 31 - blockIdx.y;        // longest-first dispatch order
  const int b = bh / NHEAD, h = bh % NHEAD;

  // ---- Q fragments in registers ----
  short8 aq[2];
#pragma unroll
  for (int kb = 0; kb < 2; kb++)
    aq[kb] = *(const short8*)&qk[(size_t)(b * S_LEN + qt * 64 + w * 16 + lm) * (2 * HID) +
                                 h * HDIM + kb * 32 + quad * 8];

  // ---- register constants ----
  const float4v z4 = (float4v)0.0f;       // C operand for first-kb MFMA
  short8 one8;                            // bf16 1.0 broadcast (B-frag of ones)
#pragma unroll
  for (int j = 0; j < 8; j++) one8[j] = (short)0x3F80;

  // ---- per-lane DMA source pointers (inverse swizzle + key permutation
  //      pre-applied; LDS dest linear; bump-by-constant each issue) ----
  const size_t kbase = (size_t)(b * S_LEN) * (2 * HID) + HID + h * HDIM;
  const size_t vbase = (size_t)(b * NHEAD + h) * HDIM * S_LEN;
  const short* kptr[2];
  const short* vptr[2];
#pragma unroll
  for (int i = 0; i < 2; i++) {
    int c = (w * 2 + i) * 64 + lane;       // LDS 16B-chunk index this lane writes
    int row = c >> 3, slot = c & 7;
    int q8 = slot ^ (row & 7);             // inverse-swizzled source chunk
    int ra = row & 15, nt = row >> 4;
    // key permutation making PV A-frag keys lane-local after swapped QK^T:
    int key = 8 * (ra >> 2) + 2 * (ra & 3) + (nt & 1) + 32 * (nt >> 1);
    kptr[i] = qk + kbase + (size_t)key * (2 * HID) + q8 * 8;
    vptr[i] = vT + vbase + (size_t)row * S_LEN + q8 * 8;
  }

#define ISSUE_K(SLOT)                                                  \
  {                                                                    \
    _Pragma("unroll") for (int i = 0; i < 2; i++) {                    \
      g2l16(kptr[i], &Ks[0][0] + (SLOT) * 4096 + (w * 2 + i) * 512);   \
      kptr[i] += 64 * 2 * HID;                                         \
    }                                                                  \
  }
#define ISSUE_V(SLOT)                                                  \
  {                                                                    \
    _Pragma("unroll") for (int i = 0; i < 2; i++) {                    \
      g2l16(vptr[i], &Vt[0][0] + (SLOT) * 4096 + (w * 2 + i) * 512);   \
      vptr[i] += 64;                                                   \
    }                                                                  \
  }

  // ---- hoisted LDS read addressing ----
  const int swx = (lm & 7) << 4;
  const int loff0 = (quad * 16) ^ swx;          // kb=0 lane part
  const int loff1 = (64 + quad * 16) ^ swx;     // kb=1 lane part
  const int rowK = lm << 7;
  const char* KsB = (const char*)&Ks[0][0];
  const char* VtB = (const char*)&Vt[0][0];

  float4v o_acc[4];
#pragma unroll
  for (int nt = 0; nt < 4; nt++) o_acc[nt] = (float4v)0.0f;
  float4v o1 = (float4v)0.0f;                   // P row-sum accumulator

#define QK_MFMA(KB0, KB1, SACC)                                                     \
  {                                                                                 \
    __builtin_amdgcn_s_setprio(1);                                                  \
    _Pragma("unroll") for (int nt = 0; nt < 4; nt++) {                              \
      short8 bk = *(const short8*)((KB0) + nt * 2048);                              \
      SACC[nt] = __builtin_amdgcn_mfma_f32_16x16x32_bf16(bk, aq[0], z4, 0, 0, 0);   \
    }                                                                               \
    _Pragma("unroll") for (int nt = 0; nt < 4; nt++) {                              \
      short8 bk = *(const short8*)((KB1) + nt * 2048);                              \
      SACC[nt] =                                                                    \
          __builtin_amdgcn_mfma_f32_16x16x32_bf16(bk, aq[1], SACC[nt], 0, 0, 0);    \
    }                                                                               \
    __builtin_amdgcn_s_setprio(0);                                                  \
  }

#define PV_MFMA(VB0, VB1, P0, P1)                                                   \
  {                                                                                 \
    __builtin_amdgcn_s_setprio(1);                                                  \
    o1 = __builtin_amdgcn_mfma_f32_16x16x32_bf16(P0, one8, o1, 0, 0, 0);            \
    _Pragma("unroll") for (int nt = 0; nt < 4; nt++) {                              \
      short8 bv = *(const short8*)((VB0) + nt * 2048);                              \
      o_acc[nt] =                                                                   \
          __builtin_amdgcn_mfma_f32_16x16x32_bf16(P0, bv, o_acc[nt], 0, 0, 0);      \
    }                                                                               \
    o1 = __builtin_amdgcn_mfma_f32_16x16x32_bf16(P1, one8, o1, 0, 0, 0);            \
    _Pragma("unroll") for (int nt = 0; nt < 4; nt++) {                              \
      short8 bv = *(const short8*)((VB1) + nt * 2048);                              \
      o_acc[nt] =                                                                   \
          __builtin_amdgcn_mfma_f32_16x16x32_bf16(P1, bv, o_acc[nt], 0, 0, 0);      \
    }                                                                               \
    __builtin_amdgcn_s_setprio(0);                                                  \
  }

// exp + pack s_acc -> two PV A-fragments (keys 32*kb+quad*8+0..7)
#define EXP_PACK(SACC, DIAG, P0, P1)                                                \
  {                                                                                 \
    float e[4][4];                                                                  \
    _Pragma("unroll") for (int nt = 0; nt < 4; nt++)                                \
      _Pragma("unroll") for (int r = 0; r < 4; r++) {                               \
        float v = fexp2(SACC[nt][r]);                                               \
        if ((DIAG) &&                                                               \
            (8 * quad + 2 * r + (nt & 1) + 32 * (nt >> 1) > w * 16 + lm))           \
          v = 0.0f;                                                                 \
        e[nt][r] = v;                                                               \
      }                                                                             \
    int4v p0i = {(int)pkbf(e[0][0], e[1][0]), (int)pkbf(e[0][1], e[1][1]),          \
                 (int)pkbf(e[0][2], e[1][2]), (int)pkbf(e[0][3], e[1][3])};         \
    int4v p1i = {(int)pkbf(e[2][0], e[3][0]), (int)pkbf(e[2][1], e[3][1]),          \
                 (int)pkbf(e[2][2], e[3][2]), (int)pkbf(e[2][3], e[3][3])};         \
    PU u0, u1;                                                                      \
    u0.i = p0i;                                                                     \
    u1.i = p1i;                                                                     \
    P0 = u0.s;                                                                      \
    P1 = u1.s;                                                                      \
  }

  const int ktmax = qt + 1;
  short8 pp0, pp1;                        // carried P of iteration kt-1

  ISSUE_K(0);
  ISSUE_V(0);

  // ---- prologue: kt = 0 (QK + exp only; PV deferred) ----
  asm volatile("s_waitcnt vmcnt(0)" ::: "memory");
  __syncthreads();
  if (ktmax > 1) { ISSUE_K(1); ISSUE_V(1); }
  {
    const char* kB0 = KsB + rowK + loff0;
    const char* kB1 = KsB + rowK + loff1;
    float4v s_acc[4];
    QK_MFMA(kB0, kB1, s_acc);
    const bool diag = (0 == qt);
    EXP_PACK(s_acc, diag, pp0, pp1);
  }

  int krd = 1;   // Ks read slot for kt
  int vwr = 2;   // Vt write slot for kt+1
  int vrd = 0;   // Vt read slot for kt-1

  for (int kt = 1; kt < ktmax; kt++) {
    // drain tile kt's DMA; fence previous iteration's LDS reads
    asm volatile("s_waitcnt vmcnt(0)" ::: "memory");
    __syncthreads();
    if (kt + 1 < ktmax) { ISSUE_K(krd ^ 1); ISSUE_V(vwr); }

    const char* kB0 = KsB + (krd << 13) + rowK + loff0;
    const char* kB1 = KsB + (krd << 13) + rowK + loff1;
    float4v s_acc[4];
    QK_MFMA(kB0, kB1, s_acc);               // QK(kt)

    const char* vB0 = VtB + (vrd << 13) + rowK + loff0;
    const char* vB1 = VtB + (vrd << 13) + rowK + loff1;
    PV_MFMA(vB0, vB1, pp0, pp1);            // PV(kt-1) — independent, overlaps

    const bool diag = (kt == qt);
    EXP_PACK(s_acc, diag, pp0, pp1);        // exp(kt) under PV's MFMA time

    krd ^= 1;
    vwr = (vwr == 2) ? 0 : vwr + 1;
    vrd = (vrd == 2) ? 0 : vrd + 1;
  }

  // ---- epilogue: PV(ktmax-1) ----
  {
    const char* vB0 = VtB + (vrd << 13) + rowK + loff0;
    const char* vB1 = VtB + (vrd << 13) + rowK + loff1;
    PV_MFMA(vB0, vB1, pp0, pp1);
  }

#pragma unroll
  for (int r = 0; r < 4; r++) {
    float inv = 1.0f / o1[r];             // row-sum from ones-MFMA (col-uniform)
    int rowg = b * S_LEN + qt * 64 + w * 16 + quad * 4 + r;
#pragma unroll
    for (int nt = 0; nt < 4; nt++)
      attnout[(size_t)rowg * HID + h * HDIM + nt * 16 + lm] =
          f2b(o_acc[nt][r] * inv);
  }
#undef ISSUE_K
#undef ISSUE_V
#undef QK_MFMA
#undef PV_MFMA
#undef EXP_PACK
}

extern "C" void kernel_launch(void* const* d_in, const int* in_sizes, int n_in,
                              void* d_out, int out_size, void* d_ws, size_t ws_size,
                              hipStream_t stream) {
  const float* x     = (const float*)d_in[0];
  const float* w_qkv = (const float*)d_in[1];
  const float* w_out = (const float*)d_in[2];
  float* out = (float*)d_out;

  const int M = BATCH * S_LEN;  // 8192
  short* qk     = (short*)d_ws;                       // [8192][1536] bf16
  short* attn   = qk + (size_t)M * 2 * HID;           // [8192][768]  bf16
  short* vT     = attn + (size_t)M * HID;             // [B][NH][64][2048] bf16
  short* xb     = vT + (size_t)M * HID;               // [8192][768]  bf16
  short* wqkvT  = xb + (size_t)M * HID;               // [2304][768]  bf16 (Q rows pre-scaled)
  short* woutT  = wqkvT + (size_t)(3 * HID) * HID;    // [768][768]   bf16

  prepass<<<3648, 256, 0, stream>>>(x, w_qkv, w_out, xb, wqkvT, woutT);

  // Q/K columns (N=1536): nwg = 12*64 = 768 (%8==0)
  gemm_bt<1><<<dim3(2 * HID / 128, M / 128), 256, 0, stream>>>(
      xb, wqkvT, nullptr, qk, nullptr, M, 2 * HID, HID);
  // V columns (N=768), swapped-operand MFMA: nwg = 6*64 = 384 (%8==0)
  gemm_bt<2><<<dim3(HID / 128, M / 128), 256, 0, stream>>>(
      xb, wqkvT + (size_t)(2 * HID) * HID, nullptr, nullptr, vT, M, HID, HID);
  // one q-tile per block; qt = 31-blockIdx.y -> longest blocks first
  attn_mfma<<<dim3(BATCH * NHEAD, 32), 256, 0, stream>>>(qk, vT, attn);
  gemm_bt<0><<<dim3(HID / 128, M / 128), 256, 0, stream>>>(
      attn, woutT, out, nullptr, nullptr, M, HID, HID);
}